// Round 4
// baseline (917.986 us; speedup 1.0000x reference)
//
#include <hip/hip_runtime.h>

#define Bn 16
#define Sn 64
#define Cn 20
#define Tn 2048
#define TPB 256

// LDS tree reduction for 256 threads, double.
__device__ __forceinline__ double block_reduce_d(double v, double* buf, int tid) {
    buf[tid] = v;
    __syncthreads();
    for (int off = 128; off > 0; off >>= 1) {
        if (tid < off) buf[tid] += buf[tid + off];
        __syncthreads();
    }
    double r = buf[0];
    __syncthreads();
    return r;
}

// ---------------- Kernel A: per-time-point MLP (fp32), fp64 row sums ----------------
// grid = B*S blocks, 256 threads.
__global__ __launch_bounds__(256) void mlp_kernel(
    const float* __restrict__ data,
    const float* __restrict__ W1, const float* __restrict__ b1,
    const float* __restrict__ W2, const float* __restrict__ b2,
    const float* __restrict__ W3, const float* __restrict__ b3,
    const float* __restrict__ W4, const float* __restrict__ b4,
    const float* __restrict__ W5, const float* __restrict__ b5,
    float* __restrict__ y, double* __restrict__ R)
{
    __shared__ float sW1[400], sW2[400], sW3[400], sW4[200], sW5[10];
    __shared__ float sb1[20], sb2[20], sb3[20], sb4[10];
    __shared__ float sb5;
    __shared__ double rbuf[TPB];

    const int tid = threadIdx.x;
    for (int i = tid; i < 400; i += TPB) { sW1[i] = W1[i]; sW2[i] = W2[i]; sW3[i] = W3[i]; }
    for (int i = tid; i < 200; i += TPB) sW4[i] = W4[i];
    if (tid < 20) { sb1[tid] = b1[tid]; sb2[tid] = b2[tid]; sb3[tid] = b3[tid]; }
    if (tid < 10) { sW5[tid] = W5[tid]; sb4[tid] = b4[tid]; }
    if (tid == 0) sb5 = b5[0];
    __syncthreads();

    const int bs = blockIdx.x;                       // b*S + s
    const float* base = data + (size_t)bs * Cn * Tn; // [c][t]
    float* yrow = y + (size_t)bs * Tn;

    double lsum = 0.0;
    for (int t = tid; t < Tn; t += TPB) {
        float x[20], h[20];
        #pragma unroll
        for (int c = 0; c < 20; ++c) x[c] = base[c * Tn + t];

        #pragma unroll
        for (int j = 0; j < 20; ++j) {           // layer 1: 20 -> 20
            float a = sb1[j];
            #pragma unroll
            for (int c = 0; c < 20; ++c) a = fmaf(x[c], sW1[c * 20 + j], a);
            h[j] = fmaxf(a, 0.f);
        }
        #pragma unroll
        for (int j = 0; j < 20; ++j) {           // layer 2: 20 -> 20
            float a = sb2[j];
            #pragma unroll
            for (int c = 0; c < 20; ++c) a = fmaf(h[c], sW2[c * 20 + j], a);
            x[j] = fmaxf(a, 0.f);
        }
        #pragma unroll
        for (int j = 0; j < 20; ++j) {           // layer 3: 20 -> 20
            float a = sb3[j];
            #pragma unroll
            for (int c = 0; c < 20; ++c) a = fmaf(x[c], sW3[c * 20 + j], a);
            h[j] = fmaxf(a, 0.f);
        }
        #pragma unroll
        for (int j = 0; j < 10; ++j) {           // layer 4: 20 -> 10
            float a = sb4[j];
            #pragma unroll
            for (int c = 0; c < 20; ++c) a = fmaf(h[c], sW4[c * 10 + j], a);
            x[j] = fmaxf(a, 0.f);
        }
        float yy = sb5;                           // layer 5: 10 -> 1
        #pragma unroll
        for (int i = 0; i < 10; ++i) yy = fmaf(x[i], sW5[i], yy);
        yy = fmaxf(yy, 0.f);

        yrow[t] = yy;
        lsum += (double)yy;
    }

    double tot = block_reduce_d(lsum, rbuf, tid);
    if (tid == 0) R[bs] = tot;   // row SUM (fp64)
}

// ---------------- Kernel B: covariance rows, all fp64 ----------------
// grid = B*S blocks (one per (b,s)); computes covd[b][s][*]
__global__ __launch_bounds__(256) void cov_kernel(
    const float* __restrict__ y, const double* __restrict__ R,
    double* __restrict__ covd)
{
    __shared__ double ysc[Tn];     // centered row s, fp64 (16 KB)
    __shared__ double rbuf[TPB];

    const int b = blockIdx.x / Sn;
    const int s = blockIdx.x % Sn;
    const int tid = threadIdx.x;

    const double ms = R[b * Sn + s] * (1.0 / Tn);
    const float* yrow = y + (size_t)(b * Sn + s) * Tn;

    double lsum = 0.0;
    for (int t = tid; t < Tn; t += TPB) {
        double v = (double)yrow[t] - ms;
        ysc[t] = v;
        lsum += v;
    }
    const double sumYsc = block_reduce_d(lsum, rbuf, tid);  // residual sum (≈0)

    for (int u = 0; u < Sn; ++u) {
        const double mu = R[b * Sn + u] * (1.0 / Tn);
        const float* yu = y + (size_t)(b * Sn + u) * Tn;
        double acc = 0.0;
        for (int t = tid; t < Tn; t += TPB)
            acc = fma((double)yu[t], ysc[t], acc);   // Sum ysc_s * y_u
        double tot = block_reduce_d(acc, rbuf, tid);
        if (tid == 0)
            covd[((size_t)b * Sn + s) * Sn + u] =
                (tot - mu * sumYsc) * (1.0 / (Tn - 1));
    }
}

// ---------------- Kernel C: corr + output (fp64 math, NaN-propagating clip) ----------------
__global__ __launch_bounds__(256) void corr_kernel(
    const double* __restrict__ covd, float* __restrict__ out)
{
    const int i = blockIdx.x * TPB + threadIdx.x;
    if (i >= Bn * Sn * Sn) return;
    const int b = i / (Sn * Sn);
    const int rem = i % (Sn * Sn);
    const int s = rem / Sn, u = rem % Sn;
    const double css = covd[((size_t)b * Sn + s) * Sn + s];
    const double cuu = covd[((size_t)b * Sn + u) * Sn + u];
    const double csu = covd[i];
    double r = csu / sqrt(css * cuu);
    // NaN-propagating clip (matches jnp.clip / np.clip semantics)
    r = (r < -1.0) ? -1.0 : ((r > 1.0) ? 1.0 : r);
    out[i] = (float)(1.0 - r);
}

extern "C" void kernel_launch(void* const* d_in, const int* in_sizes, int n_in,
                              void* d_out, int out_size, void* d_ws, size_t ws_size,
                              hipStream_t stream) {
    const float* data = (const float*)d_in[0];
    const float* W1 = (const float*)d_in[1];  const float* b1 = (const float*)d_in[2];
    const float* W2 = (const float*)d_in[3];  const float* b2 = (const float*)d_in[4];
    const float* W3 = (const float*)d_in[5];  const float* b3 = (const float*)d_in[6];
    const float* W4 = (const float*)d_in[7];  const float* b4 = (const float*)d_in[8];
    const float* W5 = (const float*)d_in[9];  const float* b5 = (const float*)d_in[10];
    float* out = (float*)d_out;

    // ws layout: y fp32 (8 MB) | covd fp64 (512 KB) | R fp64 (32 KB)
    float* y = (float*)d_ws;
    double* covd = (double*)((char*)d_ws + (size_t)Bn * Sn * Tn * sizeof(float));
    double* R = covd + (size_t)Bn * Sn * Sn;

    mlp_kernel<<<Bn * Sn, TPB, 0, stream>>>(data, W1, b1, W2, b2, W3, b3, W4, b4, W5, b5, y, R);
    cov_kernel<<<Bn * Sn, TPB, 0, stream>>>(y, R, covd);
    corr_kernel<<<(Bn * Sn * Sn + TPB - 1) / TPB, TPB, 0, stream>>>(covd, out);
}

// Round 5
// 390.890 us; speedup vs baseline: 2.3485x; 2.3485x over previous
//
#include <hip/hip_runtime.h>

#define Bn 16
#define Sn 64
#define Cn 20
#define Tn 2048
#define TPB 256

// One MLP layer for 4 time points: in[m][c] (c<20) -> out[m][j] (j<NJ), ReLU.
// WT is transposed weights in LDS: WT[j*20 + c], 16B-aligned rows (20 floats = 80 B).
template <int NJ>
__device__ __forceinline__ void layer4(const float in[4][20], float out[4][20],
                                       const float* __restrict__ WT,
                                       const float* __restrict__ bb) {
    #pragma unroll
    for (int j = 0; j < NJ; ++j) {
        float a[4] = {bb[j], bb[j], bb[j], bb[j]};
        const float4* wr = (const float4*)(WT + j * 20);
        #pragma unroll
        for (int q = 0; q < 5; ++q) {
            float4 w = wr[q];
            #pragma unroll
            for (int m = 0; m < 4; ++m) {
                a[m] = fmaf(in[m][4 * q + 0], w.x, a[m]);
                a[m] = fmaf(in[m][4 * q + 1], w.y, a[m]);
                a[m] = fmaf(in[m][4 * q + 2], w.z, a[m]);
                a[m] = fmaf(in[m][4 * q + 3], w.w, a[m]);
            }
        }
        #pragma unroll
        for (int m = 0; m < 4; ++m) out[m][j] = fmaxf(a[m], 0.f);
    }
}

// ---------------- Kernel A: per-time-point MLP (fp32), fp64 row sums ----------------
// grid = B*S blocks, 256 threads; each thread handles 4 consecutive t, 2 passes.
__global__ __launch_bounds__(256) void mlp_kernel(
    const float* __restrict__ data,
    const float* __restrict__ W1, const float* __restrict__ b1,
    const float* __restrict__ W2, const float* __restrict__ b2,
    const float* __restrict__ W3, const float* __restrict__ b3,
    const float* __restrict__ W4, const float* __restrict__ b4,
    const float* __restrict__ W5, const float* __restrict__ b5,
    float* __restrict__ y, double* __restrict__ R)
{
    __shared__ __align__(16) float sW1T[400], sW2T[400], sW3T[400], sW4T[200];
    __shared__ float sW5[10], sb1[20], sb2[20], sb3[20], sb4[10], sb5v[1];
    __shared__ double rbuf[TPB];

    const int tid = threadIdx.x;
    // stage transposed weights: sWxT[j*20+c] = Wx[c*out+j]
    for (int i = tid; i < 400; i += TPB) {
        const int j = i / 20, c = i % 20;
        sW1T[i] = W1[c * 20 + j];
        sW2T[i] = W2[c * 20 + j];
        sW3T[i] = W3[c * 20 + j];
    }
    for (int i = tid; i < 200; i += TPB) {
        const int j = i / 20, c = i % 20;
        sW4T[i] = W4[c * 10 + j];
    }
    if (tid < 20) { sb1[tid] = b1[tid]; sb2[tid] = b2[tid]; sb3[tid] = b3[tid]; }
    if (tid < 10) { sW5[tid] = W5[tid]; sb4[tid] = b4[tid]; }
    if (tid == 0) sb5v[0] = b5[0];
    __syncthreads();

    const int bs = blockIdx.x;                       // b*S + s
    const float* base = data + (size_t)bs * Cn * Tn; // [c][t]
    float* yrow = y + (size_t)bs * Tn;

    double lsum = 0.0;
    for (int pass = 0; pass < Tn / (TPB * 4); ++pass) {
        const int t0 = (pass * TPB + tid) * 4;
        float x[4][20], h[4][20];
        #pragma unroll
        for (int c = 0; c < 20; ++c) {
            const float4 v = *(const float4*)&base[c * Tn + t0];
            x[0][c] = v.x; x[1][c] = v.y; x[2][c] = v.z; x[3][c] = v.w;
        }

        layer4<20>(x, h, sW1T, sb1);   // 20 -> 20
        layer4<20>(h, x, sW2T, sb2);   // 20 -> 20
        layer4<20>(x, h, sW3T, sb3);   // 20 -> 20
        layer4<10>(h, x, sW4T, sb4);   // 20 -> 10

        float yv[4];
        #pragma unroll
        for (int m = 0; m < 4; ++m) {  // 10 -> 1
            float yy = sb5v[0];
            #pragma unroll
            for (int i = 0; i < 10; ++i) yy = fmaf(x[m][i], sW5[i], yy);
            yy = fmaxf(yy, 0.f);
            yv[m] = yy;
            lsum += (double)yy;
        }
        float4 st; st.x = yv[0]; st.y = yv[1]; st.z = yv[2]; st.w = yv[3];
        *(float4*)&yrow[t0] = st;
    }

    // block reduction (LDS tree) -> row SUM in fp64
    rbuf[tid] = lsum;
    __syncthreads();
    for (int off = 128; off > 0; off >>= 1) {
        if (tid < off) rbuf[tid] += rbuf[tid + off];
        __syncthreads();
    }
    if (tid == 0) R[bs] = rbuf[0];
}

// ---------------- Kernel B: covariance rows, fp64, barrier-free u-loop ----------------
// grid = B*S blocks (one per (b,s)); wave w owns u = w*16 .. w*16+15.
__global__ __launch_bounds__(256) void cov_kernel(
    const float* __restrict__ y, const double* __restrict__ R,
    double* __restrict__ covd)
{
    __shared__ double ysc[Tn];     // centered row s, fp64 (16 KB)
    __shared__ double rbuf[TPB];

    const int tid = threadIdx.x;
    const int lane = tid & 63, wv = tid >> 6;
    const int b = blockIdx.x >> 6;

    const double ms = R[blockIdx.x] * (1.0 / Tn);
    const float* yrow = y + (size_t)blockIdx.x * Tn;

    double lsum = 0.0;
    for (int t = tid; t < Tn; t += TPB) {
        const double v = (double)yrow[t] - ms;
        ysc[t] = v;
        lsum += v;
    }
    rbuf[tid] = lsum;
    __syncthreads();
    for (int off = 128; off > 0; off >>= 1) {
        if (tid < off) rbuf[tid] += rbuf[tid + off];
        __syncthreads();
    }
    const double sumYsc = rbuf[0];   // residual sum of centered row (≈0)

    const float* ybase = y + (size_t)(b << 6) * Tn;
    double* crow = covd + (size_t)blockIdx.x * Sn;

    for (int ui = 0; ui < 16; ++ui) {
        const int u = wv * 16 + ui;
        const float* yu = ybase + (size_t)u * Tn;
        double acc = 0.0;
        #pragma unroll
        for (int k = 0; k < Tn / 64; ++k)
            acc = fma(ysc[lane + 64 * k], (double)yu[lane + 64 * k], acc);
        #pragma unroll
        for (int off = 32; off; off >>= 1) acc += __shfl_down(acc, off, 64);
        if (lane == 0) {
            const double mu = R[(b << 6) + u] * (1.0 / Tn);
            crow[u] = (acc - mu * sumYsc) * (1.0 / (Tn - 1));
        }
    }
}

// ---------------- Kernel C: corr + output (fp64 math, NaN-propagating clip) ----------------
__global__ __launch_bounds__(256) void corr_kernel(
    const double* __restrict__ covd, float* __restrict__ out)
{
    const int i = blockIdx.x * TPB + threadIdx.x;
    if (i >= Bn * Sn * Sn) return;
    const int b = i / (Sn * Sn);
    const int rem = i % (Sn * Sn);
    const int s = rem / Sn, u = rem % Sn;
    const double css = covd[((size_t)b * Sn + s) * Sn + s];
    const double cuu = covd[((size_t)b * Sn + u) * Sn + u];
    const double csu = covd[i];
    double r = csu / sqrt(css * cuu);
    r = (r < -1.0) ? -1.0 : ((r > 1.0) ? 1.0 : r);   // NaN-propagating clip
    out[i] = (float)(1.0 - r);
}

extern "C" void kernel_launch(void* const* d_in, const int* in_sizes, int n_in,
                              void* d_out, int out_size, void* d_ws, size_t ws_size,
                              hipStream_t stream) {
    const float* data = (const float*)d_in[0];
    const float* W1 = (const float*)d_in[1];  const float* b1 = (const float*)d_in[2];
    const float* W2 = (const float*)d_in[3];  const float* b2 = (const float*)d_in[4];
    const float* W3 = (const float*)d_in[5];  const float* b3 = (const float*)d_in[6];
    const float* W4 = (const float*)d_in[7];  const float* b4 = (const float*)d_in[8];
    const float* W5 = (const float*)d_in[9];  const float* b5 = (const float*)d_in[10];
    float* out = (float*)d_out;

    // ws layout: y fp32 (8 MB) | covd fp64 (512 KB) | R fp64 (32 KB)
    float* y = (float*)d_ws;
    double* covd = (double*)((char*)d_ws + (size_t)Bn * Sn * Tn * sizeof(float));
    double* R = covd + (size_t)Bn * Sn * Sn;

    mlp_kernel<<<Bn * Sn, TPB, 0, stream>>>(data, W1, b1, W2, b2, W3, b3, W4, b4, W5, b5, y, R);
    cov_kernel<<<Bn * Sn, TPB, 0, stream>>>(y, R, covd);
    corr_kernel<<<(Bn * Sn * Sn + TPB - 1) / TPB, TPB, 0, stream>>>(covd, out);
}